// Round 1
// baseline (205.677 us; speedup 1.0000x reference)
//
#include <hip/hip_runtime.h>
#include <hip/hip_bf16.h>

// Problem constants (AggregationMPNN): B=64, N=64, E=16, H=128, M=128, OUT=128, 3 passes
#define BB 64
#define NN 64
#define EE 16
#define HH 128
#define PCOLS 640   // [HA(128) | HM(128) | GH(384)]

__device__ __forceinline__ float sigmoidf_(float x) {
    return 1.0f / (1.0f + __expf(-x));
}

// ---------------------------------------------------------------------------
// Build concatenated projection weight Wcat (128 x 640) = [Wa[:128] | Wm[:128] | Wh]
// and bias bcat (640) = [b_att | b_msg | b_h]
// ---------------------------------------------------------------------------
__global__ __launch_bounds__(256) void build_wcat(
    const float* __restrict__ Wa, const float* __restrict__ Wm, const float* __restrict__ Wh,
    const float* __restrict__ ba, const float* __restrict__ bm, const float* __restrict__ bh,
    float* __restrict__ Wcat, float* __restrict__ bcat)
{
    int idx = blockIdx.x * 256 + threadIdx.x;
    if (idx < 128 * PCOLS) {
        int k = idx / PCOLS, c = idx % PCOLS;
        float v;
        if (c < 128)       v = Wa[k * 128 + c];
        else if (c < 256)  v = Wm[k * 128 + (c - 128)];
        else               v = Wh[k * 384 + (c - 256)];
        Wcat[idx] = v;
    }
    if (idx < PCOLS) {
        float v;
        if (idx < 128)      v = ba[idx];
        else if (idx < 256) v = bm[idx - 128];
        else                v = bh[idx - 256];
        bcat[idx] = v;
    }
}

// ---------------------------------------------------------------------------
// Build compact neighbor lists from one-hot edge tensor.
// One block (= one wave of 64) per (b,i) row; lane j scans edges[b,i,j,:].
// nbr[n*64+k] = j | (etype<<8), deg[n] = neighbor count. Deterministic order (by j).
// ---------------------------------------------------------------------------
__global__ __launch_bounds__(64) void build_adj(
    const float* __restrict__ edges, int* __restrict__ nbr, int* __restrict__ deg)
{
    int n = blockIdx.x;       // b*64 + i
    int j = threadIdx.x;      // 0..63
    const float4* ep = (const float4*)&edges[(size_t)(n * NN + j) * EE];
    int et = -1;
#pragma unroll
    for (int q = 0; q < 4; q++) {
        float4 v = ep[q];
        if (v.x > 0.5f) et = q * 4 + 0;
        if (v.y > 0.5f) et = q * 4 + 1;
        if (v.z > 0.5f) et = q * 4 + 2;
        if (v.w > 0.5f) et = q * 4 + 3;
    }
    unsigned long long mask = __ballot(et >= 0);
    int pos = __popcll(mask & ((1ull << j) - 1ull));
    if (et >= 0) nbr[n * NN + pos] = j | (et << 8);
    if (j == 0) deg[n] = (int)__popcll(mask);
}

// ---------------------------------------------------------------------------
// Generic f32 GEMM: C[4096 x ncols] = A[4096 x 128] @ W[128 x ncols] (+ bias | += )
// Tiles: 32 rows x 64 cols per block, 256 threads, full K=128 staged in LDS.
// ---------------------------------------------------------------------------
__global__ __launch_bounds__(256) void gemm_k128(
    const float* __restrict__ A, const float* __restrict__ W,
    const float* __restrict__ bias, float* __restrict__ C,
    int ncols, int accum)
{
    __shared__ float As[128][34];   // transposed: As[k][row], padded stride
    __shared__ float Bs[128][64];
    int bm = blockIdx.x;            // row block (32 rows)
    int bn = blockIdx.y;            // col block (64 cols)
    int tid = threadIdx.x;
    int tx = tid & 15, ty = tid >> 4;

    // Load A tile (32 x 128), store transposed
    {
        int row = tid >> 3, kq = tid & 7;
        const float* ap = &A[(size_t)(bm * 32 + row) * HH];
#pragma unroll
        for (int s = 0; s < 4; s++) {
            int k = kq * 4 + s * 32;
            float4 a = *(const float4*)&ap[k];
            As[k + 0][row] = a.x; As[k + 1][row] = a.y;
            As[k + 2][row] = a.z; As[k + 3][row] = a.w;
        }
    }
    // Load B tile (128 x 64)
    {
        int c4 = (tid & 15) * 4;
        int kr = tid >> 4;
#pragma unroll
        for (int s = 0; s < 8; s++) {
            int k = kr + s * 16;
            float4 bv = *(const float4*)&W[(size_t)k * ncols + bn * 64 + c4];
            *(float4*)&Bs[k][c4] = bv;
        }
    }
    __syncthreads();

    float acc[2][4] = {{0.f,0.f,0.f,0.f},{0.f,0.f,0.f,0.f}};
#pragma unroll 8
    for (int k = 0; k < 128; k++) {
        float2 av = *(const float2*)&As[k][ty * 2];
        float4 bv = *(const float4*)&Bs[k][tx * 4];
        acc[0][0] += av.x * bv.x; acc[0][1] += av.x * bv.y;
        acc[0][2] += av.x * bv.z; acc[0][3] += av.x * bv.w;
        acc[1][0] += av.y * bv.x; acc[1][1] += av.y * bv.y;
        acc[1][2] += av.y * bv.z; acc[1][3] += av.y * bv.w;
    }

    int row0 = bm * 32 + ty * 2;
    int col0 = bn * 64 + tx * 4;
    if (accum) {
#pragma unroll
        for (int r = 0; r < 2; r++) {
            float* cp = &C[(size_t)(row0 + r) * ncols + col0];
            float4 o = *(const float4*)cp;
            o.x += acc[r][0]; o.y += acc[r][1]; o.z += acc[r][2]; o.w += acc[r][3];
            *(float4*)cp = o;
        }
    } else {
        float4 bv = *(const float4*)&bias[col0];
#pragma unroll
        for (int r = 0; r < 2; r++) {
            float4 o;
            o.x = acc[r][0] + bv.x; o.y = acc[r][1] + bv.y;
            o.z = acc[r][2] + bv.z; o.w = acc[r][3] + bv.w;
            *(float4*)&C[(size_t)(row0 + r) * ncols + col0] = o;
        }
    }
}

// ---------------------------------------------------------------------------
// Per-node attention message: block per (b,i), 128 threads (one per channel m).
// energy_j[m] = P_HA[b,j][m] + Wa[128+e][m] ; per-channel softmax over neighbors;
// msg[m] = sum_j att * (P_HM[b,j][m] + Wm[128+e][m]).
// Biases b_att/b_msg already folded into P via bcat.
// ---------------------------------------------------------------------------
__global__ __launch_bounds__(128) void msg_kernel(
    const float* __restrict__ P, const float* __restrict__ Wa, const float* __restrict__ Wm,
    const int* __restrict__ nbr, const int* __restrict__ deg, float* __restrict__ msg)
{
    int n = blockIdx.x;
    int d = deg[n];
    if (d == 0) return;              // message never used (node_mask==0)
    int m = threadIdx.x;
    int b = n >> 6;
    __shared__ int nb[64];
    __shared__ float E[64][128];
    if (m < 64) nb[m] = (m < d) ? nbr[n * NN + m] : 0;
    __syncthreads();

    float mx = -1e30f;
    for (int k = 0; k < d; k++) {
        int pk = nb[k];
        int j = pk & 63, e = pk >> 8;
        float en = P[(size_t)(b * NN + j) * PCOLS + m] + Wa[(128 + e) * 128 + m];
        E[k][m] = en;
        mx = fmaxf(mx, en);
    }
    float sw = 0.f, acc = 0.f;
    for (int k = 0; k < d; k++) {
        int pk = nb[k];
        int j = pk & 63, e = pk >> 8;
        float w = __expf(E[k][m] - mx);
        float em = P[(size_t)(b * NN + j) * PCOLS + 128 + m] + Wm[(128 + e) * 128 + m];
        sw += w;
        acc += w * em;
    }
    msg[(size_t)n * 128 + m] = acc / sw;
}

// ---------------------------------------------------------------------------
// Elementwise GRU update: hidden = (1-z)*n + z*hidden for deg>0 nodes.
// GI = messages@W_i + b_i (4096x384); GH in P cols 256..639 (includes b_h).
// ---------------------------------------------------------------------------
__global__ __launch_bounds__(256) void gru_kernel(
    const float* __restrict__ GI, const float* __restrict__ P,
    const int* __restrict__ deg, float* __restrict__ hidden)
{
    int idx = blockIdx.x * 256 + threadIdx.x;   // over 4096*128
    int n = idx >> 7, m = idx & 127;
    if (deg[n] == 0) return;
    float gir = GI[(size_t)n * 384 + m];
    float giz = GI[(size_t)n * 384 + 128 + m];
    float gin = GI[(size_t)n * 384 + 256 + m];
    float ghr = P[(size_t)n * PCOLS + 256 + m];
    float ghz = P[(size_t)n * PCOLS + 384 + m];
    float ghn = P[(size_t)n * PCOLS + 512 + m];
    float r  = sigmoidf_(gir + ghr);
    float z  = sigmoidf_(giz + ghz);
    float nn = tanhf(gin + r * ghn);
    float h  = hidden[idx];
    hidden[idx] = (1.f - z) * nn + z * h;
}

// ---------------------------------------------------------------------------
// Readout reduction: out[b][m] = sum_i sigmoid(GATE[n][m]) * EMB[n][m] * (deg>0)
// ---------------------------------------------------------------------------
__global__ __launch_bounds__(128) void readout2(
    const float* __restrict__ GATE, const float* __restrict__ EMB,
    const int* __restrict__ deg, float* __restrict__ out)
{
    int b = blockIdx.x, m = threadIdx.x;
    float s = 0.f;
#pragma unroll 8
    for (int i = 0; i < NN; i++) {
        int n = b * NN + i;
        if (deg[n]) {
            float g = sigmoidf_(GATE[(size_t)n * 128 + m]);
            s += g * EMB[(size_t)n * 128 + m];
        }
    }
    out[(size_t)b * 128 + m] = s;
}

// ---------------------------------------------------------------------------

extern "C" void kernel_launch(void* const* d_in, const int* in_sizes, int n_in,
                              void* d_out, int out_size, void* d_ws, size_t ws_size,
                              hipStream_t stream) {
    const float* nodes  = (const float*)d_in[0];
    const float* edges  = (const float*)d_in[1];
    const float* W_att  = (const float*)d_in[2];
    const float* b_att  = (const float*)d_in[3];
    const float* W_msg  = (const float*)d_in[4];
    const float* b_msg  = (const float*)d_in[5];
    const float* W_i    = (const float*)d_in[6];
    const float* b_i    = (const float*)d_in[7];
    const float* W_h    = (const float*)d_in[8];
    const float* b_h    = (const float*)d_in[9];
    const float* W_gate = (const float*)d_in[10];
    const float* b_gate = (const float*)d_in[11];
    const float* W_emb  = (const float*)d_in[12];
    const float* b_emb  = (const float*)d_in[13];
    float* out = (float*)d_out;

    char* ws = (char*)d_ws;
    float* Wcat   = (float*)ws; ws += 128 * PCOLS * 4;          // 320 KB
    float* bcat   = (float*)ws; ws += PCOLS * 4;                // 2.5 KB
    int*   deg    = (int*)ws;   ws += 4096 * 4;                 // 16 KB
    int*   nbr    = (int*)ws;   ws += 4096 * 64 * 4;            // 1 MB
    float* hidden = (float*)ws; ws += 4096 * 128 * 4;           // 2 MB
    float* P      = (float*)ws; ws += 4096 * PCOLS * 4;         // 10.5 MB
    float* GI     = (float*)ws; ws += 4096 * 384 * 4;           // 6.3 MB
    float* msgbuf = (float*)ws; ws += 4096 * 128 * 4;           // 2 MB
    float* EMB    = msgbuf;   // reuse after passes
    float* GATE   = GI;       // reuse after passes

    build_wcat<<<320, 256, 0, stream>>>(W_att, W_msg, W_h, b_att, b_msg, b_h, Wcat, bcat);
    build_adj<<<BB * NN, 64, 0, stream>>>(edges, nbr, deg);
    hipMemcpyAsync(hidden, nodes, (size_t)4096 * 128 * 4, hipMemcpyDeviceToDevice, stream);

    for (int p = 0; p < 3; p++) {
        gemm_k128<<<dim3(128, 10), 256, 0, stream>>>(hidden, Wcat, bcat, P, PCOLS, 0);
        msg_kernel<<<BB * NN, 128, 0, stream>>>(P, W_att, W_msg, nbr, deg, msgbuf);
        gemm_k128<<<dim3(128, 6), 256, 0, stream>>>(msgbuf, W_i, b_i, GI, 384, 0);
        gru_kernel<<<2048, 256, 0, stream>>>(GI, P, deg, hidden);
    }

    // Readout: EMB = hidden@W_emb + b_emb ; GATE = hidden@Wg[:128] + nodes@Wg[128:] + b_gate
    gemm_k128<<<dim3(128, 2), 256, 0, stream>>>(hidden, W_emb, b_emb, EMB, 128, 0);
    gemm_k128<<<dim3(128, 2), 256, 0, stream>>>(hidden, W_gate, b_gate, GATE, 128, 0);
    gemm_k128<<<dim3(128, 2), 256, 0, stream>>>(nodes, W_gate + 128 * 128, b_gate, GATE, 128, 1);
    readout2<<<BB, 128, 0, stream>>>(GATE, EMB, deg, out);
}